// Round 3
// baseline (69.656 us; speedup 1.0000x reference)
//
#include <hip/hip_runtime.h>

#define BB 4
#define NN 4096
#define TPB 1024             // 16 waves
#define IBL 32               // i's per block = 8 lane-slots x IPT=4
#define IPT 4                // i's per thread
#define STREAMS 128          // 16 waves x 8 octet-streams
#define JPT (NN / STREAMS)   // 32 j's per stream, interleaved stride 128
#define GRP 2                // LDS prefetch depth
#define RSTRIDE 100          // reduction row stride in dwords (100%32=4 -> <=2-way banks)

#if __has_builtin(__builtin_amdgcn_sqrtf)
  #define FAST_SQRT __builtin_amdgcn_sqrtf
#else
  #define FAST_SQRT sqrtf
#endif

__device__ __forceinline__ float clip1(float x) {
    return fminf(fmaxf(x, -1.0f), 1.0f);   // -> v_med3_f32
}

// sd for an i-PAIR against one j, via packed fp32 (VOP3P v_pk_fma_f32).
// lo half = even i, hi half = odd i. j-components broadcast via op_sel:
//   t  = m2x2 * x.bcast + w.bcast      (x = cxy.lo, w = czw.hi)
//   t  = m2y2 * y.bcast + t            (y = cxy.hi)
//   sd = m2z2 * z.bcast + t            (z = czw.lo)
// Identical arithmetic to the scalar version (same fma order), co-issued 2x.
__device__ __forceinline__ float2 sd_pair(float2 m2x2, float2 m2y2, float2 m2z2,
                                          float2 cxy, float2 czw)
{
    float2 t, d;
    asm("v_pk_fma_f32 %0, %1, %2, %3 op_sel:[0,0,1] op_sel_hi:[1,0,1]"
        : "=v"(t) : "v"(m2x2), "v"(cxy), "v"(czw));
    asm("v_pk_fma_f32 %0, %1, %2, %3 op_sel:[0,1,0] op_sel_hi:[1,1,1]"
        : "=v"(t) : "v"(m2y2), "v"(cxy), "v"(t));
    asm("v_pk_fma_f32 %0, %1, %2, %3 op_sel:[0,0,0] op_sel_hi:[1,0,1]"
        : "=v"(d) : "v"(m2z2), "v"(czw), "v"(t));
    return d;
}

// Taken path (16.5% of per-u wave tests): unchanged math from R2.
__device__ __forceinline__ void hit(float sd, float thrv, float riv,
    float m2xv, float m2yv, float m2zv,
    float cx, float cy, float cz, float rjv,
    float& ax, float& ay, float& az)
{
    const float sp1  = 1.0f + riv;
    const float n2   = fmaf(sp1, sp1, -thrv);      // = ||pi||^2
    const float dist = FAST_SQRT(fmaxf(sd + n2, 0.0f));
    const float tgt  = fmaxf(1.0f, riv + rjv);
    const float p    = fmaxf(tgt - dist, 0.0f);
    const float ex   = fmaf(0.5f, m2xv, cx);       // = -dx; diag -> exact 0
    const float ey   = fmaf(0.5f, m2yv, cy);
    const float ez   = fmaf(0.5f, m2zv, cz);
    ax = fmaf(p, -clip1(ex), ax);                  // neg folds to modifier
    ay = fmaf(p, -clip1(ey), ay);
    az = fmaf(p, -clip1(ez), az);
}

// R3 = R2 skeleton (512 blocks = 2/CU, 32 waves/CU, conflict-free interleaved
// j-streams, vectorized staging, tree epilogue) + PACKED miss path:
// v_pk_fma_f32 over i-pairs cuts the dominant VALU-issue term (12 fma/j ->
// 6 pk_fma/j). Per-u __any branch granularity preserved (packed halves are
// individual VGPRs). Floor probe rule: if this moves <0.5us, the remaining
// ~68us is harness floor (40us ws-repoison fill at 84% HBM peak + gaps) and
// the answer is ROOFLINE.
__global__ __launch_bounds__(TPB, 8) void ncp_one(
    const float* __restrict__ coords,   // [BB,NN,3]
    const float* __restrict__ radii,    // [BB,NN]
    float* __restrict__ out)
{
    __shared__ __align__(16) char smem[81920];   // 64 KB pts4 + 16 KB rad
    float4* pts = (float4*)smem;            // [NN] (x,y,z,||p||^2)
    float*  rad = (float*)(smem + 65536);   // [NN]
    float*  red = (float*)smem;             // phase 2: [STREAMS][RSTRIDE] (50 KB)
    float*  red2 = (float*)(smem + 65536);  // phase 2b: [4][96] partials

    const int b = blockIdx.z;
    const int ibase = blockIdx.x * IBL;
    const int t = threadIdx.x;

    {   // vectorized staging: 4 consecutive points per thread, 48 B coords
        const float4* cb = (const float4*)(coords + (size_t)b * NN * 3);
        const float4  f0 = cb[3 * t + 0];
        const float4  f1 = cb[3 * t + 1];
        const float4  f2 = cb[3 * t + 2];
        const float4  r4 = ((const float4*)(radii + (size_t)b * NN))[t];
        const int p0 = 4 * t;
        pts[p0 + 0] = make_float4(f0.x, f0.y, f0.z,
                                  fmaf(f0.z, f0.z, fmaf(f0.y, f0.y, f0.x * f0.x)));
        pts[p0 + 1] = make_float4(f0.w, f1.x, f1.y,
                                  fmaf(f1.y, f1.y, fmaf(f1.x, f1.x, f0.w * f0.w)));
        pts[p0 + 2] = make_float4(f1.z, f1.w, f2.x,
                                  fmaf(f2.x, f2.x, fmaf(f1.w, f1.w, f1.z * f1.z)));
        pts[p0 + 3] = make_float4(f2.y, f2.z, f2.w,
                                  fmaf(f2.w, f2.w, fmaf(f2.z, f2.z, f2.y * f2.y)));
        *(float4*)&rad[p0] = r4;
    }
    __syncthreads();

    const int l  = t & 63;
    const int li = l & 7;               // i lane-slot 0..7
    const int o  = l >> 3;              // octet 0..7
    const int w  = t >> 6;              // wave 0..15
    const int s  = w * 8 + o;           // stream 0..127: j = s + k*128

    // packed per-i constants: pp in {0,1} covers u = 2pp (lo), 2pp+1 (hi)
    float2 m2xp[2], m2yp[2], m2zp[2];
    float thr[IPT], ri[IPT];
    float ax[IPT], ay[IPT], az[IPT];
    #pragma unroll
    for (int u = 0; u < IPT; ++u) {
        const float4 me = pts[ibase + li + 8 * u];
        const float  r  = rad[ibase + li + 8 * u];
        ((float*)m2xp)[u] = -2.0f * me.x;
        ((float*)m2yp)[u] = -2.0f * me.y;
        ((float*)m2zp)[u] = -2.0f * me.z;
        ri[u]  = r;
        thr[u] = (1.0f + r) * (1.0f + r) - me.w;   // tight skip bound
        ax[u] = 0.0f; ay[u] = 0.0f; az[u] = 0.0f;
    }

    const float4* __restrict__ pj = pts + s;   // stride-128 j walk
    const float*  __restrict__ rj = rad + s;

    for (int k0 = 0; k0 < JPT; k0 += GRP) {
        float4 c[GRP];
        #pragma unroll
        for (int g = 0; g < GRP; ++g)
            c[g] = pj[(k0 + g) * STREAMS];      // conflict-free 8-way broadcast
        #pragma unroll
        for (int g = 0; g < GRP; ++g) {
            // float4 from ds_read_b128 is even-aligned: halves alias, no movs
            const float2 cxy = make_float2(c[g].x, c[g].y);
            const float2 czw = make_float2(c[g].z, c[g].w);
            #pragma unroll
            for (int pp = 0; pp < 2; ++pp) {
                const float2 sd = sd_pair(m2xp[pp], m2yp[pp], m2zp[pp], cxy, czw);
                const int u0 = 2 * pp, u1 = 2 * pp + 1;
                if (__any(sd.x < thr[u0])) {
                    const float rjv = rj[(k0 + g) * STREAMS];   // taken only
                    hit(sd.x, thr[u0], ri[u0],
                        m2xp[pp].x, m2yp[pp].x, m2zp[pp].x,
                        c[g].x, c[g].y, c[g].z, rjv, ax[u0], ay[u0], az[u0]);
                }
                if (__any(sd.y < thr[u1])) {
                    const float rjv = rj[(k0 + g) * STREAMS];
                    hit(sd.y, thr[u1], ri[u1],
                        m2xp[pp].y, m2yp[pp].y, m2zp[pp].y,
                        c[g].x, c[g].y, c[g].z, rjv, ax[u1], ay[u1], az[u1]);
                }
            }
        }
    }

    __syncthreads();                    // all pts/rad reads done before reuse
    #pragma unroll
    for (int u = 0; u < IPT; ++u) {
        const int r0 = s * RSTRIDE + (li + 8 * u) * 3;
        red[r0 + 0] = ax[u];
        red[r0 + 1] = ay[u];
        red[r0 + 2] = az[u];
    }
    __syncthreads();

    if (t < 384) {                      // level 1: 4 chunks x 32 streams
        const int oc    = t % 96;       // output component 0..95
        const int chunk = t / 96;       // 0..3
        float acc = 0.0f;
        const int sbase = chunk * 32;
        #pragma unroll 8
        for (int ss = 0; ss < 32; ++ss)     // ascending ss == ascending j
            acc += red[(sbase + ss) * RSTRIDE + oc];
        red2[chunk * 96 + oc] = acc;
    }
    __syncthreads();

    if (t < 96) {                       // level 2: 4 partials + writeout
        const float acc = ((red2[t] + red2[96 + t]) + red2[192 + t]) + red2[288 + t];
        const int oidx = (b * NN + ibase) * 3 + t;
        out[oidx] = fmaf(0.1f / (float)NN, acc, coords[oidx]);
    }
}

extern "C" void kernel_launch(void* const* d_in, const int* in_sizes, int n_in,
                              void* d_out, int out_size, void* d_ws, size_t ws_size,
                              hipStream_t stream) {
    const float* coords = (const float*)d_in[0];
    const float* radii  = (const float*)d_in[1];
    float* out = (float*)d_out;
    (void)d_ws; (void)ws_size;

    ncp_one<<<dim3(NN / IBL, 1, BB), TPB, 0, stream>>>(coords, radii, out);
}